// Round 1
// baseline (8055.811 us; speedup 1.0000x reference)
//
#include <hip/hip_runtime.h>
#include <math.h>

// Problem constants (match reference)
//   N=50000, D_IN=512, HID=256, HEADS=4, OUT=64, MLP_H=128, K=4, L=2
static constexpr int MROWS = 50000;

// =====================================================================
// Generic tiled FP32 GEMM:  C = act(A @ B + bias), row-major, strided batch
// =====================================================================
template<int BM, int BN, int BK, int TM, int TN, bool RELU>
__global__ __launch_bounds__(256) void sgemm_kernel(
    const float* __restrict__ A, const float* __restrict__ B,
    const float* __restrict__ bias, float* __restrict__ C,
    int M, int K, int lda, int ldb, int ldc,
    size_t sA, size_t sB, size_t sBias, size_t sC)
{
    constexpr int TX = BN / TN;
    constexpr int TY = BM / TM;
    static_assert(TX * TY == 256, "tile/thread mismatch");

    A    += (size_t)blockIdx.z * sA;
    B    += (size_t)blockIdx.z * sB;
    bias += (size_t)blockIdx.z * sBias;
    C    += (size_t)blockIdx.z * sC;

    __shared__ __align__(16) float As[BK][BM + 4];
    __shared__ __align__(16) float Bs[BK][BN + 4];

    const int tid  = threadIdx.x;
    const int row0 = blockIdx.y * BM;
    const int col0 = blockIdx.x * BN;
    const int ty   = tid / TX;
    const int tx   = tid % TX;

    float acc[TM][TN];
#pragma unroll
    for (int i = 0; i < TM; i++)
#pragma unroll
        for (int j = 0; j < TN; j++) acc[i][j] = 0.f;

    constexpr int KV        = BK / 4;                 // float4 groups along k
    constexpr int A_ITERS   = (BM * BK) / (256 * 4);
    constexpr int AR_STRIDE = 256 / KV;
    constexpr int BN4       = BN / 4;
    constexpr int B_ITERS   = (BK * BN) / (256 * 4);
    constexpr int BK_STRIDE = 256 / BN4;

    const int ar_base = tid / KV;
    const int ak      = (tid % KV) * 4;
    const int bk_base = tid / BN4;
    const int bn      = (tid % BN4) * 4;

    for (int k0 = 0; k0 < K; k0 += BK) {
#pragma unroll
        for (int it = 0; it < A_ITERS; it++) {
            int ar = ar_base + it * AR_STRIDE;
            int gr = row0 + ar; gr = gr < M ? gr : M - 1;   // clamp (stores guarded)
            float4 av = *(const float4*)(A + (size_t)gr * lda + (k0 + ak));
            As[ak + 0][ar] = av.x;
            As[ak + 1][ar] = av.y;
            As[ak + 2][ar] = av.z;
            As[ak + 3][ar] = av.w;
        }
#pragma unroll
        for (int it = 0; it < B_ITERS; it++) {
            int bk = bk_base + it * BK_STRIDE;
            float4 bv = *(const float4*)(B + (size_t)(k0 + bk) * ldb + (col0 + bn));
            *(float4*)&Bs[bk][bn] = bv;
        }
        __syncthreads();
#pragma unroll
        for (int kk = 0; kk < BK; kk++) {
            float a[TM], b[TN];
#pragma unroll
            for (int i = 0; i < TM; i += 4)
                *(float4*)&a[i] = *(const float4*)&As[kk][ty * TM + i];
#pragma unroll
            for (int j = 0; j < TN; j += 4)
                *(float4*)&b[j] = *(const float4*)&Bs[kk][tx * TN + j];
#pragma unroll
            for (int i = 0; i < TM; i++)
#pragma unroll
                for (int j = 0; j < TN; j++)
                    acc[i][j] = fmaf(a[i], b[j], acc[i][j]);
        }
        __syncthreads();
    }

#pragma unroll
    for (int i = 0; i < TM; i++) {
        int r = row0 + ty * TM + i;
        if (r >= M) continue;
#pragma unroll
        for (int j = 0; j < TN; j += 4) {
            int c = col0 + tx * TN + j;
            float4 bv = *(const float4*)(bias + c);
            float4 o;
            o.x = acc[i][j + 0] + bv.x;
            o.y = acc[i][j + 1] + bv.y;
            o.z = acc[i][j + 2] + bv.z;
            o.w = acc[i][j + 3] + bv.w;
            if (RELU) {
                o.x = fmaxf(o.x, 0.f); o.y = fmaxf(o.y, 0.f);
                o.z = fmaxf(o.z, 0.f); o.w = fmaxf(o.w, 0.f);
            }
            *(float4*)(C + (size_t)r * ldc + c) = o;
        }
    }
}

// =====================================================================
// LayerNorm(+ReLU) over 256 cols, one wave per row (4 rows / 256-thread block)
// =====================================================================
__global__ __launch_bounds__(256) void ln_relu_kernel(
    const float* __restrict__ in, const float* __restrict__ w, const float* __restrict__ b,
    float* __restrict__ out, int M)
{
    int row  = blockIdx.x * 4 + (threadIdx.x >> 6);
    int lane = threadIdx.x & 63;
    if (row >= M) return;
    float4 v = *(const float4*)(in + (size_t)row * 256 + lane * 4);
    float s  = v.x + v.y + v.z + v.w;
    float ss = v.x * v.x + v.y * v.y + v.z * v.z + v.w * v.w;
#pragma unroll
    for (int m = 1; m < 64; m <<= 1) {
        s  += __shfl_xor(s, m, 64);
        ss += __shfl_xor(ss, m, 64);
    }
    float mu  = s * (1.f / 256.f);
    float var = ss * (1.f / 256.f) - mu * mu;
    float inv = rsqrtf(var + 1e-5f);
    float4 wv = *(const float4*)(w + lane * 4);
    float4 bv = *(const float4*)(b + lane * 4);
    float4 o;
    o.x = fmaxf((v.x - mu) * inv * wv.x + bv.x, 0.f);
    o.y = fmaxf((v.y - mu) * inv * wv.y + bv.y, 0.f);
    o.z = fmaxf((v.z - mu) * inv * wv.z + bv.z, 0.f);
    o.w = fmaxf((v.w - mu) * inv * wv.w + bv.w, 0.f);
    *(float4*)(out + (size_t)row * 256 + lane * 4) = o;
}

// =====================================================================
// Stats over X[M,1024]: ssq (global sum of squares, atomic) and optional
// per-column sums (ks_sum). grid.x = 4 colgroups * 32 row chunks = 128
// =====================================================================
__global__ __launch_bounds__(256) void stats_kernel(
    const float* __restrict__ X, int M, float* __restrict__ ssq_out,
    float* __restrict__ colsum)
{
    const int col      = (blockIdx.x & 3) * 256 + threadIdx.x;
    const int chunk    = blockIdx.x >> 2;
    const int rows_per = (M + 31) / 32;
    const int r0 = chunk * rows_per;
    const int r1 = min(M, r0 + rows_per);
    float cs = 0.f, sq = 0.f;
    for (int r = r0; r < r1; r++) {
        float v = X[(size_t)r * 1024 + col];
        cs += v;
        sq += v * v;
    }
    if (colsum) atomicAdd(&colsum[col], cs);
    __shared__ float red[256];
    red[threadIdx.x] = sq;
    __syncthreads();
    for (int st = 128; st > 0; st >>= 1) {
        if (threadIdx.x < st) red[threadIdx.x] += red[threadIdx.x + st];
        __syncthreads();
    }
    if (threadIdx.x == 0) atomicAdd(ssq_out, red[0]);
}

// =====================================================================
// kvs[h][m][d] = sum_n K[n, h*256+m] * V[n, h*256+d]
// grid: x = 64 tiles (h*16 + m-tile*4 + d-tile), y = n-chunks (8). atomics.
// =====================================================================
__global__ __launch_bounds__(256) void kvs_kernel(
    const float* __restrict__ Kp, const float* __restrict__ Vp,
    float* __restrict__ kvs, int M)
{
    const int h  = blockIdx.x >> 4;
    const int m0 = ((blockIdx.x >> 2) & 3) * 64;
    const int d0 = (blockIdx.x & 3) * 64;
    const int rows_per = (M + gridDim.y - 1) / gridDim.y;
    const int n0 = blockIdx.y * rows_per;
    const int n1 = min(M, n0 + rows_per);

    __shared__ __align__(16) float Ks[32][68];
    __shared__ __align__(16) float Vs[32][68];

    const int tid = threadIdx.x;
    const int tx = tid % 16, ty = tid / 16;
    float acc[4][4];
#pragma unroll
    for (int i = 0; i < 4; i++)
#pragma unroll
        for (int j = 0; j < 4; j++) acc[i][j] = 0.f;

    for (int nb = n0; nb < n1; nb += 32) {
#pragma unroll
        for (int i = 0; i < 2; i++) {
            int r = tid / 16 + i * 16;
            int c = (tid % 16) * 4;
            int gr = nb + r;
            float4 kv = {0, 0, 0, 0}, vv = {0, 0, 0, 0};
            if (gr < n1) {
                kv = *(const float4*)(Kp + (size_t)gr * 1024 + h * 256 + m0 + c);
                vv = *(const float4*)(Vp + (size_t)gr * 1024 + h * 256 + d0 + c);
            }
            *(float4*)&Ks[r][c] = kv;
            *(float4*)&Vs[r][c] = vv;
        }
        __syncthreads();
#pragma unroll
        for (int i = 0; i < 32; i++) {
            float am[4], bd[4];
            *(float4*)am = *(const float4*)&Ks[i][ty * 4];
            *(float4*)bd = *(const float4*)&Vs[i][tx * 4];
#pragma unroll
            for (int mi = 0; mi < 4; mi++)
#pragma unroll
                for (int di = 0; di < 4; di++)
                    acc[mi][di] = fmaf(am[mi], bd[di], acc[mi][di]);
        }
        __syncthreads();
    }
#pragma unroll
    for (int mi = 0; mi < 4; mi++)
#pragma unroll
        for (int di = 0; di < 4; di++)
            atomicAdd(&kvs[(size_t)h * 65536 + (size_t)(m0 + ty * 4 + mi) * 256 + d0 + tx * 4 + di],
                      acc[mi][di]);
}

// =====================================================================
// den[n][h] = sum_m Q[n, h*256+m] * ks[h*256+m]   (raw, unscaled)
// one wave per row; lane covers 16 cols; 16-lane groups = heads
// =====================================================================
__global__ __launch_bounds__(256) void den_kernel(
    const float* __restrict__ Q, const float* __restrict__ ks,
    float* __restrict__ den, int M)
{
    int row  = blockIdx.x * 4 + (threadIdx.x >> 6);
    int lane = threadIdx.x & 63;
    if (row >= M) return;
    float p = 0.f;
    const float* qr = Q + (size_t)row * 1024 + lane * 16;
    const float* kr = ks + lane * 16;
#pragma unroll
    for (int j = 0; j < 16; j += 4) {
        float4 qv = *(const float4*)(qr + j);
        float4 kv = *(const float4*)(kr + j);
        p += qv.x * kv.x + qv.y * kv.y + qv.z * kv.z + qv.w * kv.w;
    }
#pragma unroll
    for (int m = 1; m < 16; m <<= 1) p += __shfl_xor(p, m, 64);
    if ((lane & 15) == 0) den[(size_t)row * 4 + (lane >> 4)] = p;
}

// =====================================================================
// Fused attention epilogue per 64-row block:
//  for h in 4: acc = Q_h @ kvs_h ; fin += (acc*s + n*V_h) / (den_h*s + n)
//  out = relu(LN(fin/4*0.5 + hin*0.5))
// threads: tx(0..15) = 16-col group, ty(0..15) = 4-row group
// =====================================================================
__global__ __launch_bounds__(256) void attn_fuse_kernel(
    const float* __restrict__ Q, const float* __restrict__ V,
    const float* __restrict__ kvs, const float* __restrict__ den,
    const float* __restrict__ ssq,
    const float* __restrict__ hin,
    const float* __restrict__ lnw, const float* __restrict__ lnb,
    float* __restrict__ hout, int M)
{
    const int row0 = blockIdx.x * 64;
    const int tid  = threadIdx.x;
    const int tx   = tid % 16;
    const int ty   = tid / 16;
    const float s  = rsqrtf(ssq[0]) * rsqrtf(ssq[1]);   // 1/(||k||*||q||)
    const float nn = 50000.f;

    __shared__ __align__(16) float As[16][68];        // k-chunk x 64 rows
    __shared__ __align__(16) float Bs[16][16][20];    // k-chunk x (16 colgroups x 16+pad)

    float fin[4][16];
#pragma unroll
    for (int i = 0; i < 4; i++)
#pragma unroll
        for (int j = 0; j < 16; j++) fin[i][j] = 0.f;

    for (int h = 0; h < 4; h++) {
        float acc[4][16];
#pragma unroll
        for (int i = 0; i < 4; i++)
#pragma unroll
            for (int j = 0; j < 16; j++) acc[i][j] = 0.f;

        for (int k0 = 0; k0 < 256; k0 += 16) {
            {   // stage Q tile (64 rows x 16 k), transposed
                int r  = tid >> 2;
                int k4 = (tid & 3) * 4;
                int gr = row0 + r; gr = gr < M ? gr : M - 1;
                float4 qv = *(const float4*)(Q + (size_t)gr * 1024 + h * 256 + k0 + k4);
                As[k4 + 0][r] = qv.x;
                As[k4 + 1][r] = qv.y;
                As[k4 + 2][r] = qv.z;
                As[k4 + 3][r] = qv.w;
            }
#pragma unroll
            for (int i = 0; i < 4; i++) {   // stage kvs chunk (16 k x 256 d)
                int k    = (tid >> 6) + i * 4;
                int lane = tid & 63;
                int cg   = lane >> 2;
                int ci   = (lane & 3) * 4;
                *(float4*)&Bs[k][cg][ci] =
                    *(const float4*)(kvs + (size_t)h * 65536 + (size_t)(k0 + k) * 256 + lane * 4);
            }
            __syncthreads();
#pragma unroll
            for (int kk = 0; kk < 16; kk++) {
                float a[4], b[16];
                *(float4*)a = *(const float4*)&As[kk][ty * 4];
#pragma unroll
                for (int j4 = 0; j4 < 4; j4++)
                    *(float4*)&b[j4 * 4] = *(const float4*)&Bs[kk][tx][j4 * 4];
#pragma unroll
                for (int i = 0; i < 4; i++)
#pragma unroll
                    for (int j = 0; j < 16; j++)
                        acc[i][j] = fmaf(a[i], b[j], acc[i][j]);
            }
            __syncthreads();
        }
        // per-head epilogue
#pragma unroll
        for (int i = 0; i < 4; i++) {
            int r  = row0 + ty * 4 + i;
            int rr = r < M ? r : M - 1;
            float dh  = den[(size_t)rr * 4 + h] * s + nn;
            float rdh = 1.f / dh;
#pragma unroll
            for (int j = 0; j < 16; j += 4) {
                float4 vv = *(const float4*)(V + (size_t)rr * 1024 + h * 256 + tx * 16 + j);
                fin[i][j + 0] += (acc[i][j + 0] * s + nn * vv.x) * rdh;
                fin[i][j + 1] += (acc[i][j + 1] * s + nn * vv.y) * rdh;
                fin[i][j + 2] += (acc[i][j + 2] * s + nn * vv.z) * rdh;
                fin[i][j + 3] += (acc[i][j + 3] * s + nn * vv.w) * rdh;
            }
        }
    }

    // head-mean, residual, LayerNorm, ReLU
#pragma unroll
    for (int i = 0; i < 4; i++) {
        int r  = row0 + ty * 4 + i;
        int rr = r < M ? r : M - 1;
        float xv[16];
#pragma unroll
        for (int j = 0; j < 16; j += 4) {
            float4 hv = *(const float4*)(hin + (size_t)rr * 256 + tx * 16 + j);
            xv[j + 0] = fin[i][j + 0] * 0.125f + hv.x * 0.5f;
            xv[j + 1] = fin[i][j + 1] * 0.125f + hv.y * 0.5f;
            xv[j + 2] = fin[i][j + 2] * 0.125f + hv.z * 0.5f;
            xv[j + 3] = fin[i][j + 3] * 0.125f + hv.w * 0.5f;
        }
        float sm = 0.f, sq = 0.f;
#pragma unroll
        for (int j = 0; j < 16; j++) { sm += xv[j]; sq += xv[j] * xv[j]; }
#pragma unroll
        for (int m = 1; m < 16; m <<= 1) {
            sm += __shfl_xor(sm, m, 64);
            sq += __shfl_xor(sq, m, 64);
        }
        float mu  = sm * (1.f / 256.f);
        float var = sq * (1.f / 256.f) - mu * mu;
        float inv = rsqrtf(var + 1e-5f);
        if (r < M) {
#pragma unroll
            for (int j = 0; j < 16; j++) {
                int c = tx * 16 + j;
                float y = (xv[j] - mu) * inv * lnw[c] + lnb[c];
                hout[(size_t)r * 256 + c] = fmaxf(y, 0.f);
            }
        }
    }
}

// =====================================================================
// log_softmax over 256 cols + combine with x1: comb = 0.5*(x-lse) + 0.5*x1
// =====================================================================
__global__ __launch_bounds__(256) void lsm_combine_kernel(
    const float* __restrict__ logits, const float* __restrict__ x1,
    float* __restrict__ comb, int M)
{
    int row  = blockIdx.x * 4 + (threadIdx.x >> 6);
    int lane = threadIdx.x & 63;
    if (row >= M) return;
    float4 v = *(const float4*)(logits + (size_t)row * 256 + lane * 4);
    float mx = fmaxf(fmaxf(v.x, v.y), fmaxf(v.z, v.w));
#pragma unroll
    for (int m = 1; m < 64; m <<= 1) mx = fmaxf(mx, __shfl_xor(mx, m, 64));
    float e = expf(v.x - mx) + expf(v.y - mx) + expf(v.z - mx) + expf(v.w - mx);
#pragma unroll
    for (int m = 1; m < 64; m <<= 1) e += __shfl_xor(e, m, 64);
    float lse = mx + logf(e);
    float4 xv = *(const float4*)(x1 + (size_t)row * 256 + lane * 4);
    float4 o;
    o.x = 0.5f * (v.x - lse) + 0.5f * xv.x;
    o.y = 0.5f * (v.y - lse) + 0.5f * xv.y;
    o.z = 0.5f * (v.z - lse) + 0.5f * xv.z;
    o.w = 0.5f * (v.w - lse) + 0.5f * xv.w;
    *(float4*)(comb + (size_t)row * 256 + lane * 4) = o;
}

// =====================================================================
extern "C" void kernel_launch(void* const* d_in, const int* in_sizes, int n_in,
                              void* d_out, int out_size, void* d_ws, size_t ws_size,
                              hipStream_t stream)
{
    (void)in_sizes; (void)n_in; (void)out_size; (void)ws_size;

    const float* x         = (const float*)d_in[0];
    // d_in[1] = edge_index (unused by the reference computation)
    const float* xs        = (const float*)d_in[2];
    const float* fc0_w     = (const float*)d_in[3];
    const float* fc0_b     = (const float*)d_in[4];
    const float* ln_w      = (const float*)d_in[5];
    const float* ln_b      = (const float*)d_in[6];
    const float* Wq_w      = (const float*)d_in[7];
    const float* Wq_b      = (const float*)d_in[8];
    const float* Wk_w      = (const float*)d_in[9];
    const float* Wk_b      = (const float*)d_in[10];
    const float* Wv_w      = (const float*)d_in[11];
    const float* Wv_b      = (const float*)d_in[12];
    const float* mlp_w     = (const float*)d_in[13];
    const float* mlp_b     = (const float*)d_in[14];
    const float* mlp_lin_w = (const float*)d_in[15];
    const float* mlp_lin_b = (const float*)d_in[16];
    const float* fc_w      = (const float*)d_in[17];
    const float* fc_b      = (const float*)d_in[18];
    float* out = (float*)d_out;

    const int M = MROWS;

    // Workspace layout (floats): ~514 MB total
    float* hA   = (float*)d_ws;                 // [M,256]
    float* hB   = hA + (size_t)M * 256;         // [M,256]
    float* bigA = hB + (size_t)M * 256;         // [M,1024]  (k, then q; later SIGN feats [M,512])
    float* bigB = bigA + (size_t)M * 1024;      // [M,1024]  (v; later logits [M,256])
    float* kvs  = bigB + (size_t)M * 1024;      // [4,256,256]
    float* ks   = kvs + 4 * 256 * 256;          // [1024]
    float* ssq  = ks + 1024;                    // [2]  (0: ssq_k, 1: ssq_q)
    float* den  = ssq + 2;                      // [M,4]

    dim3 blk(256);
    const int GY  = (M + 127) / 128;            // 391
    const int GY2 = (M + 63) / 64;              // 782

    // ---- fc0 + bias -> pre-LN (bigA), then LN+ReLU -> hA ----
    sgemm_kernel<128, 128, 16, 8, 8, false><<<dim3(2, GY), blk, 0, stream>>>(
        x, fc0_w, fc0_b, bigA, M, 512, 512, 256, 256, 0, 0, 0, 0);
    ln_relu_kernel<<<dim3((M + 3) / 4), blk, 0, stream>>>(bigA, ln_w, ln_b, hA, M);

    // ---- 2 TransConv layers ----
    const float* hin = hA;
    float* hout = hB;
    for (int l = 0; l < 2; l++) {
        hipMemsetAsync(kvs, 0, (4 * 256 * 256 + 1024 + 2) * sizeof(float), stream);
        // V
        sgemm_kernel<128, 128, 16, 8, 8, false><<<dim3(8, GY), blk, 0, stream>>>(
            hin, Wv_w + (size_t)l * 256 * 1024, Wv_b + l * 1024, bigB,
            M, 256, 256, 1024, 1024, 0, 0, 0, 0);
        // K
        sgemm_kernel<128, 128, 16, 8, 8, false><<<dim3(8, GY), blk, 0, stream>>>(
            hin, Wk_w + (size_t)l * 256 * 1024, Wk_b + l * 1024, bigA,
            M, 256, 256, 1024, 1024, 0, 0, 0, 0);
        stats_kernel<<<dim3(128), blk, 0, stream>>>(bigA, M, ssq + 0, ks);
        kvs_kernel<<<dim3(64, 8), blk, 0, stream>>>(bigA, bigB, kvs, M);
        // Q (overwrites K buffer)
        sgemm_kernel<128, 128, 16, 8, 8, false><<<dim3(8, GY), blk, 0, stream>>>(
            hin, Wq_w + (size_t)l * 256 * 1024, Wq_b + l * 1024, bigA,
            M, 256, 256, 1024, 1024, 0, 0, 0, 0);
        stats_kernel<<<dim3(128), blk, 0, stream>>>(bigA, M, ssq + 1, nullptr);
        den_kernel<<<dim3((M + 3) / 4), blk, 0, stream>>>(bigA, ks, den, M);
        attn_fuse_kernel<<<dim3(GY2), blk, 0, stream>>>(
            bigA, bigB, kvs, den, ssq, hin,
            ln_w + (size_t)(l + 1) * 256, ln_b + (size_t)(l + 1) * 256, hout, M);
        const float* t = hin; hin = hout; hout = (float*)t;
    }
    const float* x1 = hin;   // == hA after 2 layers; hB is free scratch

    // ---- SIGN branch: feats (4 batched GEMMs with ReLU) -> bigA [M,512] ----
    sgemm_kernel<128, 128, 16, 8, 8, true><<<dim3(1, GY, 4), blk, 0, stream>>>(
        xs, mlp_w, mlp_b, bigA, M, 512, 512, 128, 512,
        (size_t)M * 512, (size_t)512 * 128, 128, 128);
    // logits -> bigB [M,256]
    sgemm_kernel<128, 128, 16, 8, 8, false><<<dim3(2, GY), blk, 0, stream>>>(
        bigA, mlp_lin_w, mlp_lin_b, bigB, M, 512, 512, 256, 256, 0, 0, 0, 0);
    // log_softmax + combine with x1 -> hB
    lsm_combine_kernel<<<dim3((M + 3) / 4), blk, 0, stream>>>(bigB, x1, hB, M);
    // final fc -> out
    sgemm_kernel<64, 64, 16, 4, 4, false><<<dim3(1, GY2), blk, 0, stream>>>(
        hB, fc_w, fc_b, out, M, 256, 256, 64, 64, 0, 0, 0, 0);
}

// Round 2
// 6267.127 us; speedup vs baseline: 1.2854x; 1.2854x over previous
//
#include <hip/hip_runtime.h>
#include <math.h>

static constexpr int MROWS = 50000;

typedef __attribute__((ext_vector_type(8))) __bf16 bf16x8;
typedef __attribute__((ext_vector_type(4))) float f32x4;

__device__ __forceinline__ float b2f(unsigned short h) {
    return __uint_as_float(((unsigned)h) << 16);
}
__device__ __forceinline__ unsigned short f2b(float x) {
    unsigned u = __float_as_uint(x);
    return (unsigned short)((u + 0x7fffu + ((u >> 16) & 1u)) >> 16);
}

typedef const __attribute__((address_space(1))) void gv_t;
typedef __attribute__((address_space(3))) void lv_t;
__device__ __forceinline__ void gload16(const void* g, void* l) {
    __builtin_amdgcn_global_load_lds((gv_t*)g, (lv_t*)l, 16, 0, 0);
}

// =====================================================================
// Split-bf16 MFMA GEMM: C = act(rec(A) @ rec(B)^T-stored + bias)
// A as hi/lo bf16 [M,Kd] row-major; B as hi/lo bf16 BT[N,Kd] row-major.
// 128x128 tile, BK=32, 4 waves, mfma_f32_16x16x32_bf16, 3 MFMAs per frag.
// MODE 0: f32 out. MODE 1: bf16 hi/lo out.
// =====================================================================
template<int MODE, bool RELU>
__global__ __launch_bounds__(256) void mgemm_kernel(
    const unsigned short* __restrict__ Ahi, const unsigned short* __restrict__ Alo,
    const unsigned short* __restrict__ Bhi, const unsigned short* __restrict__ Blo,
    const float* __restrict__ bias,
    float* __restrict__ Cf, unsigned short* __restrict__ Chi, unsigned short* __restrict__ Clo,
    int M, int Kd, int ldc,
    long sA, long sB, long sBias, long sC)
{
    const int tid = threadIdx.x;
    const int w = tid >> 6, l = tid & 63;
    const int wm = w >> 1, wn = w & 1;
    const long bz = blockIdx.z;
    Ahi += bz * sA; Alo += bz * sA;
    Bhi += bz * sB; Blo += bz * sB;

    const int row0 = blockIdx.y * 128;
    const int col0 = blockIdx.x * 128;

    __shared__ __align__(16) char lds[32768];
    // tiles (bytes): Ahi@0, Alo@8192, Bhi@16384, Blo@24576; each [128 rows][32 k] bf16

    f32x4 zero = {0.f, 0.f, 0.f, 0.f};
    f32x4 acc[4][4];
#pragma unroll
    for (int i = 0; i < 4; i++)
#pragma unroll
        for (int j = 0; j < 4; j++) acc[i][j] = zero;

    // staging geometry: lane covers LDS tile byte ofs = c*4096 + w*1024 + l*16
    const int sofs = w * 1024 + l * 16;
    const int trow = sofs >> 6;            // tile row (0..63), +64 for chunk 1
    const int tk   = (sofs & 63) >> 1;     // k elem start (0,8,16,24)
    int ar0 = row0 + trow;      ar0 = ar0 < M ? ar0 : M - 1;
    int ar1 = row0 + trow + 64; ar1 = ar1 < M ? ar1 : M - 1;
    const size_t aoff0 = (size_t)ar0 * Kd + tk;
    const size_t aoff1 = (size_t)ar1 * Kd + tk;
    const size_t boff0 = (size_t)(col0 + trow) * Kd + tk;
    const size_t boff1 = (size_t)(col0 + trow + 64) * Kd + tk;
    char* ldst = lds + w * 1024;

    for (int k0 = 0; k0 < Kd; k0 += 32) {
        gload16(Ahi + aoff0 + k0, ldst + 0);
        gload16(Ahi + aoff1 + k0, ldst + 4096);
        gload16(Alo + aoff0 + k0, ldst + 8192);
        gload16(Alo + aoff1 + k0, ldst + 12288);
        gload16(Bhi + boff0 + k0, ldst + 16384);
        gload16(Bhi + boff1 + k0, ldst + 20480);
        gload16(Blo + boff0 + k0, ldst + 24576);
        gload16(Blo + boff1 + k0, ldst + 28672);
        __syncthreads();

        const int rl = l & 15, q = l >> 4;
        bf16x8 ah[4], al[4];
#pragma unroll
        for (int i = 0; i < 4; i++) {
            const int ab = ((wm * 64 + i * 16 + rl) << 6) + q * 16;
            ah[i] = *(const bf16x8*)(lds + ab);
            al[i] = *(const bf16x8*)(lds + 8192 + ab);
        }
#pragma unroll
        for (int j = 0; j < 4; j++) {
            const int bb = ((wn * 64 + j * 16 + rl) << 6) + q * 16;
            bf16x8 bh = *(const bf16x8*)(lds + 16384 + bb);
            bf16x8 bl = *(const bf16x8*)(lds + 24576 + bb);
#pragma unroll
            for (int i = 0; i < 4; i++) {
                acc[i][j] = __builtin_amdgcn_mfma_f32_16x16x32_bf16(ah[i], bh, acc[i][j], 0, 0, 0);
                acc[i][j] = __builtin_amdgcn_mfma_f32_16x16x32_bf16(ah[i], bl, acc[i][j], 0, 0, 0);
                acc[i][j] = __builtin_amdgcn_mfma_f32_16x16x32_bf16(al[i], bh, acc[i][j], 0, 0, 0);
            }
        }
        __syncthreads();
    }

    // epilogue: D col = lane&15, row = (lane>>4)*4 + reg   [m89-verified]
    const int rl = l & 15, q = l >> 4;
#pragma unroll
    for (int j = 0; j < 4; j++) {
        const int gcol = col0 + wn * 64 + j * 16 + rl;
        const float bv = bias ? bias[bz * sBias + gcol] : 0.f;
#pragma unroll
        for (int i = 0; i < 4; i++) {
            const int rb = row0 + wm * 64 + i * 16 + q * 4;
#pragma unroll
            for (int rg = 0; rg < 4; rg++) {
                const int r = rb + rg;
                if (r < M) {
                    float v = acc[i][j][rg] + bv;
                    if (RELU) v = fmaxf(v, 0.f);
                    const size_t ci = (size_t)r * ldc + bz * sC + gcol;
                    if (MODE == 0) {
                        Cf[ci] = v;
                    } else {
                        unsigned short h = f2b(v);
                        Chi[ci] = h;
                        Clo[ci] = f2b(v - b2f(h));
                    }
                }
            }
        }
    }
}

// =====================================================================
// f32 -> bf16 hi/lo split (4 elems/thread)
// =====================================================================
__global__ __launch_bounds__(256) void split_kernel(
    const float* __restrict__ X, long n4,
    unsigned short* __restrict__ Hi, unsigned short* __restrict__ Lo)
{
    long e = (long)blockIdx.x * 256 + threadIdx.x;
    if (e >= n4) return;
    float4 v = *(const float4*)(X + e * 4);
    ushort4 h, lo;
    h.x = f2b(v.x); lo.x = f2b(v.x - b2f(h.x));
    h.y = f2b(v.y); lo.y = f2b(v.y - b2f(h.y));
    h.z = f2b(v.z); lo.z = f2b(v.z - b2f(h.z));
    h.w = f2b(v.w); lo.w = f2b(v.w - b2f(h.w));
    *(ushort4*)(Hi + e * 4) = h;
    *(ushort4*)(Lo + e * 4) = lo;
}

// =====================================================================
// weight transpose + split: W f32 [B][Kd][Nd] -> WT hi/lo [B][Nd][Kd]
// =====================================================================
__global__ __launch_bounds__(256) void wtsplit_kernel(
    const float* __restrict__ W, long Bn, long Kd, long Nd,
    unsigned short* __restrict__ Thi, unsigned short* __restrict__ Tlo)
{
    long e = (long)blockIdx.x * 256 + threadIdx.x;
    long kn = Kd * Nd;
    if (e >= Bn * kn) return;
    long b = e / kn, r = e % kn;
    long n = r / Kd, k = r % Kd;
    float v = W[b * kn + k * Nd + n];
    unsigned short h = f2b(v);
    Thi[e] = h;
    Tlo[e] = f2b(v - b2f(h));
}

// =====================================================================
// kvs f32 [4][256(m)][256(d)] -> kvsT hi/lo laid out [256(d)][1024(h*256+m)]
// =====================================================================
__global__ __launch_bounds__(256) void ktsplit_kernel(
    const float* __restrict__ kvsf,
    unsigned short* __restrict__ Thi, unsigned short* __restrict__ Tlo)
{
    int e = blockIdx.x * 256 + threadIdx.x;   // over 262144
    int d = e >> 10, h = (e >> 8) & 3, m = e & 255;
    float v = kvsf[(h << 16) | (m << 8) | d];
    unsigned short hi = f2b(v);
    Thi[e] = hi;
    Tlo[e] = f2b(v - b2f(hi));
}

// =====================================================================
// LayerNorm+ReLU over 256 cols from f32 input, output bf16 hi/lo
// =====================================================================
__global__ __launch_bounds__(256) void ln_relu_split_kernel(
    const float* __restrict__ in, const float* __restrict__ w, const float* __restrict__ b,
    unsigned short* __restrict__ Ohi, unsigned short* __restrict__ Olo, int M)
{
    int row  = blockIdx.x * 4 + (threadIdx.x >> 6);
    int lane = threadIdx.x & 63;
    if (row >= M) return;
    float4 v = *(const float4*)(in + (size_t)row * 256 + lane * 4);
    float s  = v.x + v.y + v.z + v.w;
    float ss = v.x * v.x + v.y * v.y + v.z * v.z + v.w * v.w;
#pragma unroll
    for (int m = 1; m < 64; m <<= 1) {
        s  += __shfl_xor(s, m, 64);
        ss += __shfl_xor(ss, m, 64);
    }
    float mu  = s * (1.f / 256.f);
    float var = ss * (1.f / 256.f) - mu * mu;
    float inv = rsqrtf(var + 1e-5f);
    float4 wv = *(const float4*)(w + lane * 4);
    float4 bv = *(const float4*)(b + lane * 4);
    float y[4];
    y[0] = fmaxf((v.x - mu) * inv * wv.x + bv.x, 0.f);
    y[1] = fmaxf((v.y - mu) * inv * wv.y + bv.y, 0.f);
    y[2] = fmaxf((v.z - mu) * inv * wv.z + bv.z, 0.f);
    y[3] = fmaxf((v.w - mu) * inv * wv.w + bv.w, 0.f);
    ushort4 h, lo;
    h.x = f2b(y[0]); lo.x = f2b(y[0] - b2f(h.x));
    h.y = f2b(y[1]); lo.y = f2b(y[1] - b2f(h.y));
    h.z = f2b(y[2]); lo.z = f2b(y[2] - b2f(h.z));
    h.w = f2b(y[3]); lo.w = f2b(y[3] - b2f(h.w));
    *(ushort4*)(Ohi + (size_t)row * 256 + lane * 4) = h;
    *(ushort4*)(Olo + (size_t)row * 256 + lane * 4) = lo;
}

// =====================================================================
// Stats over bf16-pair X[M,1024]: global ssq (atomic) + optional col sums
// =====================================================================
__global__ __launch_bounds__(256) void stats_kernel(
    const unsigned short* __restrict__ Xhi, const unsigned short* __restrict__ Xlo,
    int M, float* __restrict__ ssq_out, float* __restrict__ colsum)
{
    const int col      = (blockIdx.x & 3) * 256 + threadIdx.x;
    const int chunk    = blockIdx.x >> 2;
    const int rows_per = (M + 31) / 32;
    const int r0 = chunk * rows_per;
    const int r1 = min(M, r0 + rows_per);
    float cs = 0.f, sq = 0.f;
    for (int r = r0; r < r1; r++) {
        float v = b2f(Xhi[(size_t)r * 1024 + col]) + b2f(Xlo[(size_t)r * 1024 + col]);
        cs += v;
        sq += v * v;
    }
    if (colsum) atomicAdd(&colsum[col], cs);
    __shared__ float red[256];
    red[threadIdx.x] = sq;
    __syncthreads();
    for (int st = 128; st > 0; st >>= 1) {
        if (threadIdx.x < st) red[threadIdx.x] += red[threadIdx.x + st];
        __syncthreads();
    }
    if (threadIdx.x == 0) atomicAdd(ssq_out, red[0]);
}

// =====================================================================
// kvs[h][m][d] = sum_n K[n,h*256+m] * V[n,h*256+d]  (bf16-pair inputs)
// =====================================================================
__global__ __launch_bounds__(256) void kvs_kernel(
    const unsigned short* __restrict__ Khi, const unsigned short* __restrict__ Klo,
    const unsigned short* __restrict__ Vhi, const unsigned short* __restrict__ Vlo,
    float* __restrict__ kvs, int M)
{
    const int h  = blockIdx.x >> 4;
    const int m0 = ((blockIdx.x >> 2) & 3) * 64;
    const int d0 = (blockIdx.x & 3) * 64;
    const int rows_per = (M + gridDim.y - 1) / gridDim.y;
    const int n0 = blockIdx.y * rows_per;
    const int n1 = min(M, n0 + rows_per);

    __shared__ __align__(16) float Ks[32][68];
    __shared__ __align__(16) float Vs[32][68];

    const int tid = threadIdx.x;
    const int tx = tid % 16, ty = tid / 16;
    float acc[4][4];
#pragma unroll
    for (int i = 0; i < 4; i++)
#pragma unroll
        for (int j = 0; j < 4; j++) acc[i][j] = 0.f;

    for (int nb = n0; nb < n1; nb += 32) {
#pragma unroll
        for (int i = 0; i < 2; i++) {
            int r = tid / 16 + i * 16;
            int c = (tid % 16) * 4;
            int gr = nb + r;
            float4 kv = {0, 0, 0, 0}, vv = {0, 0, 0, 0};
            if (gr < n1) {
                ushort4 a = *(const ushort4*)(Khi + (size_t)gr * 1024 + h * 256 + m0 + c);
                ushort4 b = *(const ushort4*)(Klo + (size_t)gr * 1024 + h * 256 + m0 + c);
                kv.x = b2f(a.x) + b2f(b.x); kv.y = b2f(a.y) + b2f(b.y);
                kv.z = b2f(a.z) + b2f(b.z); kv.w = b2f(a.w) + b2f(b.w);
                ushort4 c1 = *(const ushort4*)(Vhi + (size_t)gr * 1024 + h * 256 + d0 + c);
                ushort4 c2 = *(const ushort4*)(Vlo + (size_t)gr * 1024 + h * 256 + d0 + c);
                vv.x = b2f(c1.x) + b2f(c2.x); vv.y = b2f(c1.y) + b2f(c2.y);
                vv.z = b2f(c1.z) + b2f(c2.z); vv.w = b2f(c1.w) + b2f(c2.w);
            }
            *(float4*)&Ks[r][c] = kv;
            *(float4*)&Vs[r][c] = vv;
        }
        __syncthreads();
#pragma unroll
        for (int i = 0; i < 32; i++) {
            float am[4], bd[4];
            *(float4*)am = *(const float4*)&Ks[i][ty * 4];
            *(float4*)bd = *(const float4*)&Vs[i][tx * 4];
#pragma unroll
            for (int mi = 0; mi < 4; mi++)
#pragma unroll
                for (int di = 0; di < 4; di++)
                    acc[mi][di] = fmaf(am[mi], bd[di], acc[mi][di]);
        }
        __syncthreads();
    }
#pragma unroll
    for (int mi = 0; mi < 4; mi++)
#pragma unroll
        for (int di = 0; di < 4; di++)
            atomicAdd(&kvs[(size_t)h * 65536 + (size_t)(m0 + ty * 4 + mi) * 256 + d0 + tx * 4 + di],
                      acc[mi][di]);
}

// =====================================================================
// den[n][h] = sum_m Q[n,h*256+m] * ks[h*256+m]  (raw)
// =====================================================================
__global__ __launch_bounds__(256) void den_kernel(
    const unsigned short* __restrict__ Qhi, const unsigned short* __restrict__ Qlo,
    const float* __restrict__ ks, float* __restrict__ den, int M)
{
    int row  = blockIdx.x * 4 + (threadIdx.x >> 6);
    int lane = threadIdx.x & 63;
    if (row >= M) return;
    float p = 0.f;
    const unsigned short* qh = Qhi + (size_t)row * 1024 + lane * 16;
    const unsigned short* ql = Qlo + (size_t)row * 1024 + lane * 16;
    const float* kr = ks + lane * 16;
#pragma unroll
    for (int j = 0; j < 16; j += 4) {
        ushort4 a = *(const ushort4*)(qh + j);
        ushort4 b = *(const ushort4*)(ql + j);
        float4 kv = *(const float4*)(kr + j);
        p += (b2f(a.x) + b2f(b.x)) * kv.x + (b2f(a.y) + b2f(b.y)) * kv.y
           + (b2f(a.z) + b2f(b.z)) * kv.z + (b2f(a.w) + b2f(b.w)) * kv.w;
    }
#pragma unroll
    for (int m = 1; m < 16; m <<= 1) p += __shfl_xor(p, m, 64);
    if ((lane & 15) == 0) den[(size_t)row * 4 + (lane >> 4)] = p;
}

// =====================================================================
// Q' = Q * s * rdh(n,h) in-place (bf16 pair), folding scales into GEMM A
// =====================================================================
__global__ __launch_bounds__(256) void qscale_kernel(
    unsigned short* __restrict__ Qhi, unsigned short* __restrict__ Qlo,
    const float* __restrict__ den, const float* __restrict__ ssq, int M)
{
    size_t e = ((size_t)blockIdx.x * 256 + threadIdx.x) * 4;
    if (e >= (size_t)M * 1024) return;
    const float s = rsqrtf(ssq[0]) * rsqrtf(ssq[1]);
    const int n = (int)(e >> 10), h = (int)((e >> 8) & 3);
    const float f = s / (den[(size_t)n * 4 + h] * s + 50000.f);
    ushort4 qh = *(const ushort4*)(Qhi + e);
    ushort4 ql = *(const ushort4*)(Qlo + e);
    float v[4];
    v[0] = (b2f(qh.x) + b2f(ql.x)) * f;
    v[1] = (b2f(qh.y) + b2f(ql.y)) * f;
    v[2] = (b2f(qh.z) + b2f(ql.z)) * f;
    v[3] = (b2f(qh.w) + b2f(ql.w)) * f;
    ushort4 oh, ol;
    oh.x = f2b(v[0]); ol.x = f2b(v[0] - b2f(oh.x));
    oh.y = f2b(v[1]); ol.y = f2b(v[1] - b2f(oh.y));
    oh.z = f2b(v[2]); ol.z = f2b(v[2] - b2f(oh.z));
    oh.w = f2b(v[3]); ol.w = f2b(v[3] - b2f(oh.w));
    *(ushort4*)(Qhi + e) = oh;
    *(ushort4*)(Qlo + e) = ol;
}

// =====================================================================
// attention epilogue: x = (fin + sum_h n*v*rdh)/4*0.5 + 0.5*hin ; LN; ReLU
// =====================================================================
__global__ __launch_bounds__(256) void attn_ep_kernel(
    const float* __restrict__ fin,
    const unsigned short* __restrict__ Vhi, const unsigned short* __restrict__ Vlo,
    const float* __restrict__ den, const float* __restrict__ ssq,
    const unsigned short* __restrict__ hinhi, const unsigned short* __restrict__ hinlo,
    const float* __restrict__ lnw, const float* __restrict__ lnb,
    unsigned short* __restrict__ houthi, unsigned short* __restrict__ houtlo, int M)
{
    const int row  = blockIdx.x * 4 + (threadIdx.x >> 6);
    const int lane = threadIdx.x & 63;
    if (row >= M) return;
    const int d4 = lane * 4;
    const float s = rsqrtf(ssq[0]) * rsqrtf(ssq[1]);
    const float nn = 50000.f;
    float4 f = *(const float4*)(fin + (size_t)row * 256 + d4);
    float4 dn = *(const float4*)(den + (size_t)row * 4);
    float t[4] = {f.x, f.y, f.z, f.w};
    const float rd[4] = {nn / (dn.x * s + nn), nn / (dn.y * s + nn),
                         nn / (dn.z * s + nn), nn / (dn.w * s + nn)};
#pragma unroll
    for (int h = 0; h < 4; h++) {
        ushort4 vh = *(const ushort4*)(Vhi + (size_t)row * 1024 + h * 256 + d4);
        ushort4 vl = *(const ushort4*)(Vlo + (size_t)row * 1024 + h * 256 + d4);
        t[0] += (b2f(vh.x) + b2f(vl.x)) * rd[h];
        t[1] += (b2f(vh.y) + b2f(vl.y)) * rd[h];
        t[2] += (b2f(vh.z) + b2f(vl.z)) * rd[h];
        t[3] += (b2f(vh.w) + b2f(vl.w)) * rd[h];
    }
    ushort4 hh = *(const ushort4*)(hinhi + (size_t)row * 256 + d4);
    ushort4 hl = *(const ushort4*)(hinlo + (size_t)row * 256 + d4);
    float xv[4];
    xv[0] = t[0] * 0.125f + 0.5f * (b2f(hh.x) + b2f(hl.x));
    xv[1] = t[1] * 0.125f + 0.5f * (b2f(hh.y) + b2f(hl.y));
    xv[2] = t[2] * 0.125f + 0.5f * (b2f(hh.z) + b2f(hl.z));
    xv[3] = t[3] * 0.125f + 0.5f * (b2f(hh.w) + b2f(hl.w));
    float sm = xv[0] + xv[1] + xv[2] + xv[3];
    float sq = xv[0]*xv[0] + xv[1]*xv[1] + xv[2]*xv[2] + xv[3]*xv[3];
#pragma unroll
    for (int m = 1; m < 64; m <<= 1) {
        sm += __shfl_xor(sm, m, 64);
        sq += __shfl_xor(sq, m, 64);
    }
    float mu  = sm * (1.f / 256.f);
    float var = sq * (1.f / 256.f) - mu * mu;
    float inv = rsqrtf(var + 1e-5f);
    float4 wv = *(const float4*)(lnw + d4);
    float4 bv = *(const float4*)(lnb + d4);
    float y[4];
    y[0] = fmaxf((xv[0] - mu) * inv * wv.x + bv.x, 0.f);
    y[1] = fmaxf((xv[1] - mu) * inv * wv.y + bv.y, 0.f);
    y[2] = fmaxf((xv[2] - mu) * inv * wv.z + bv.z, 0.f);
    y[3] = fmaxf((xv[3] - mu) * inv * wv.w + bv.w, 0.f);
    ushort4 oh, ol;
    oh.x = f2b(y[0]); ol.x = f2b(y[0] - b2f(oh.x));
    oh.y = f2b(y[1]); ol.y = f2b(y[1] - b2f(oh.y));
    oh.z = f2b(y[2]); ol.z = f2b(y[2] - b2f(oh.z));
    oh.w = f2b(y[3]); ol.w = f2b(y[3] - b2f(oh.w));
    *(ushort4*)(houthi + (size_t)row * 256 + d4) = oh;
    *(ushort4*)(houtlo + (size_t)row * 256 + d4) = ol;
}

// =====================================================================
// log_softmax + combine: comb = 0.5*(logits - lse) + 0.5*rec(x1)
// =====================================================================
__global__ __launch_bounds__(256) void lsm_combine_kernel(
    const float* __restrict__ logits,
    const unsigned short* __restrict__ x1hi, const unsigned short* __restrict__ x1lo,
    float* __restrict__ comb, int M)
{
    int row  = blockIdx.x * 4 + (threadIdx.x >> 6);
    int lane = threadIdx.x & 63;
    if (row >= M) return;
    float4 v = *(const float4*)(logits + (size_t)row * 256 + lane * 4);
    float mx = fmaxf(fmaxf(v.x, v.y), fmaxf(v.z, v.w));
#pragma unroll
    for (int m = 1; m < 64; m <<= 1) mx = fmaxf(mx, __shfl_xor(mx, m, 64));
    float e = expf(v.x - mx) + expf(v.y - mx) + expf(v.z - mx) + expf(v.w - mx);
#pragma unroll
    for (int m = 1; m < 64; m <<= 1) e += __shfl_xor(e, m, 64);
    float lse = mx + logf(e);
    ushort4 xh = *(const ushort4*)(x1hi + (size_t)row * 256 + lane * 4);
    ushort4 xl = *(const ushort4*)(x1lo + (size_t)row * 256 + lane * 4);
    float4 o;
    o.x = 0.5f * (v.x - lse) + 0.5f * (b2f(xh.x) + b2f(xl.x));
    o.y = 0.5f * (v.y - lse) + 0.5f * (b2f(xh.y) + b2f(xl.y));
    o.z = 0.5f * (v.z - lse) + 0.5f * (b2f(xh.z) + b2f(xl.z));
    o.w = 0.5f * (v.w - lse) + 0.5f * (b2f(xh.w) + b2f(xl.w));
    *(float4*)(comb + (size_t)row * 256 + lane * 4) = o;
}

// =====================================================================
// fp32 tiled GEMM (final fc only, N=64)
// =====================================================================
template<int BM, int BN, int BK, int TM, int TN, bool RELU>
__global__ __launch_bounds__(256) void sgemm_kernel(
    const float* __restrict__ A, const float* __restrict__ B,
    const float* __restrict__ bias, float* __restrict__ C,
    int M, int K, int lda, int ldb, int ldc,
    size_t sA, size_t sB, size_t sBias, size_t sC)
{
    constexpr int TX = BN / TN;
    constexpr int TY = BM / TM;
    static_assert(TX * TY == 256, "tile/thread mismatch");

    A    += (size_t)blockIdx.z * sA;
    B    += (size_t)blockIdx.z * sB;
    bias += (size_t)blockIdx.z * sBias;
    C    += (size_t)blockIdx.z * sC;

    __shared__ __align__(16) float As[BK][BM + 4];
    __shared__ __align__(16) float Bs[BK][BN + 4];

    const int tid  = threadIdx.x;
    const int row0 = blockIdx.y * BM;
    const int col0 = blockIdx.x * BN;
    const int ty   = tid / TX;
    const int tx   = tid % TX;

    float acc[TM][TN];
#pragma unroll
    for (int i = 0; i < TM; i++)
#pragma unroll
        for (int j = 0; j < TN; j++) acc[i][j] = 0.f;

    constexpr int KV        = BK / 4;
    constexpr int A_ITERS   = (BM * BK) / (256 * 4);
    constexpr int AR_STRIDE = 256 / KV;
    constexpr int BN4       = BN / 4;
    constexpr int B_ITERS   = (BK * BN) / (256 * 4);
    constexpr int BK_STRIDE = 256 / BN4;

    const int ar_base = tid / KV;
    const int ak      = (tid % KV) * 4;
    const int bk_base = tid / BN4;
    const int bn      = (tid % BN4) * 4;

    for (int k0 = 0; k0 < K; k0 += BK) {
#pragma unroll
        for (int it = 0; it < A_ITERS; it++) {
            int ar = ar_base + it * AR_STRIDE;
            int gr = row0 + ar; gr = gr < M ? gr : M - 1;
            float4 av = *(const float4*)(A + (size_t)gr * lda + (k0 + ak));
            As[ak + 0][ar] = av.x;
            As[ak + 1][ar] = av.y;
            As[ak + 2][ar] = av.z;
            As[ak + 3][ar] = av.w;
        }
#pragma unroll
        for (int it = 0; it < B_ITERS; it++) {
            int bk = bk_base + it * BK_STRIDE;
            float4 bv = *(const float4*)(B + (size_t)(k0 + bk) * ldb + (col0 + bn));
            *(float4*)&Bs[bk][bn] = bv;
        }
        __syncthreads();
#pragma unroll
        for (int kk = 0; kk < BK; kk++) {
            float a[TM], b[TN];
#pragma unroll
            for (int i = 0; i < TM; i += 4)
                *(float4*)&a[i] = *(const float4*)&As[kk][ty * TM + i];
#pragma unroll
            for (int j = 0; j < TN; j += 4)
                *(float4*)&b[j] = *(const float4*)&Bs[kk][tx * TN + j];
#pragma unroll
            for (int i = 0; i < TM; i++)
#pragma unroll
                for (int j = 0; j < TN; j++)
                    acc[i][j] = fmaf(a[i], b[j], acc[i][j]);
        }
        __syncthreads();
    }

#pragma unroll
    for (int i = 0; i < TM; i++) {
        int r = row0 + ty * TM + i;
        if (r >= M) continue;
#pragma unroll
        for (int j = 0; j < TN; j += 4) {
            int c = col0 + tx * TN + j;
            float4 bv = *(const float4*)(bias + c);
            float4 o;
            o.x = acc[i][j + 0] + bv.x;
            o.y = acc[i][j + 1] + bv.y;
            o.z = acc[i][j + 2] + bv.z;
            o.w = acc[i][j + 3] + bv.w;
            if (RELU) {
                o.x = fmaxf(o.x, 0.f); o.y = fmaxf(o.y, 0.f);
                o.z = fmaxf(o.z, 0.f); o.w = fmaxf(o.w, 0.f);
            }
            *(float4*)(C + (size_t)r * ldc + c) = o;
        }
    }
}

// =====================================================================
extern "C" void kernel_launch(void* const* d_in, const int* in_sizes, int n_in,
                              void* d_out, int out_size, void* d_ws, size_t ws_size,
                              hipStream_t stream)
{
    (void)in_sizes; (void)n_in; (void)out_size; (void)ws_size;

    const float* x         = (const float*)d_in[0];
    const float* xs        = (const float*)d_in[2];
    const float* fc0_w     = (const float*)d_in[3];
    const float* fc0_b     = (const float*)d_in[4];
    const float* ln_w      = (const float*)d_in[5];
    const float* ln_b      = (const float*)d_in[6];
    const float* Wq_w      = (const float*)d_in[7];
    const float* Wq_b      = (const float*)d_in[8];
    const float* Wk_w      = (const float*)d_in[9];
    const float* Wk_b      = (const float*)d_in[10];
    const float* Wv_w      = (const float*)d_in[11];
    const float* Wv_b      = (const float*)d_in[12];
    const float* mlp_w     = (const float*)d_in[13];
    const float* mlp_b     = (const float*)d_in[14];
    const float* mlp_lin_w = (const float*)d_in[15];
    const float* mlp_lin_b = (const float*)d_in[16];
    const float* fc_w      = (const float*)d_in[17];
    const float* fc_b      = (const float*)d_in[18];
    float* out = (float*)d_out;

    const int M = MROWS;
    char* Bp = (char*)d_ws;

    const size_t SZ_P = 204800000;   // [M,1024] bf16 pair
    unsigned short* P1  = (unsigned short*)Bp;
    unsigned short* P2  = (unsigned short*)(Bp + SZ_P);
    unsigned short* HAh = (unsigned short*)(Bp + 2 * SZ_P);
    unsigned short* HAl = (unsigned short*)(Bp + 2 * SZ_P + 25600000);
    unsigned short* HBh = (unsigned short*)(Bp + 2 * SZ_P + 51200000);
    unsigned short* HBl = (unsigned short*)(Bp + 2 * SZ_P + 76800000);
    float*          FINf= (float*)(Bp + 2 * SZ_P + 102400000);   // 51.2 MB
    char* Wp = Bp + 2 * SZ_P + 153600000;

    size_t wo = 0;
    auto nxt = [&](size_t bytes) { char* p = Wp + wo; wo += (bytes + 255) & ~(size_t)255; return p; };
    unsigned short* fc0Th = (unsigned short*)nxt(262144);
    unsigned short* fc0Tl = (unsigned short*)nxt(262144);
    unsigned short* WqTh  = (unsigned short*)nxt(1048576);
    unsigned short* WqTl  = (unsigned short*)nxt(1048576);
    unsigned short* WkTh  = (unsigned short*)nxt(1048576);
    unsigned short* WkTl  = (unsigned short*)nxt(1048576);
    unsigned short* WvTh  = (unsigned short*)nxt(1048576);
    unsigned short* WvTl  = (unsigned short*)nxt(1048576);
    unsigned short* mwTh  = (unsigned short*)nxt(524288);
    unsigned short* mwTl  = (unsigned short*)nxt(524288);
    unsigned short* mlTh  = (unsigned short*)nxt(262144);
    unsigned short* mlTl  = (unsigned short*)nxt(262144);
    float* kvsf  = (float*)nxt(1048576);
    float* ks    = (float*)nxt(4096);
    float* ssq   = (float*)nxt(256);
    unsigned short* kvsTh = (unsigned short*)nxt(524288);
    unsigned short* kvsTl = (unsigned short*)nxt(524288);
    float* den   = (float*)nxt(800000);

    // aliases (element offsets on ushort*)
    unsigned short* xhi = P1;            unsigned short* xlo = P1 + 25600000;
    unsigned short* Khi = P1;            unsigned short* Klo = P1 + 51200000;
    unsigned short* Qhi = P1;            unsigned short* Qlo = P1 + 51200000;
    unsigned short* Vhi = P2;            unsigned short* Vlo = P2 + 51200000;
    unsigned short* Xsh = P1;            unsigned short* Xsl = P2;
    unsigned short* feath = (unsigned short*)FINf;   // [M,512]
    unsigned short* featl = HBh;                     // [M,512] spans HB region
    float* logitsf = (float*)P2;
    float* combf   = (float*)P1;

    dim3 blk(256);
    const int GY = (M + 127) / 128;   // 391

    // ---- weight transforms + input split ----
    wtsplit_kernel<<<dim3(512), blk, 0, stream>>>(fc0_w, 1, 512, 256, fc0Th, fc0Tl);
    wtsplit_kernel<<<dim3(2048), blk, 0, stream>>>(Wq_w, 2, 256, 1024, WqTh, WqTl);
    wtsplit_kernel<<<dim3(2048), blk, 0, stream>>>(Wk_w, 2, 256, 1024, WkTh, WkTl);
    wtsplit_kernel<<<dim3(2048), blk, 0, stream>>>(Wv_w, 2, 256, 1024, WvTh, WvTl);
    wtsplit_kernel<<<dim3(1024), blk, 0, stream>>>(mlp_w, 4, 512, 128, mwTh, mwTl);
    wtsplit_kernel<<<dim3(512), blk, 0, stream>>>(mlp_lin_w, 1, 512, 256, mlTh, mlTl);
    split_kernel<<<dim3(25000), blk, 0, stream>>>(x, (long)M * 512 / 4, xhi, xlo);

    // ---- fc0 -> preLN(FINf) -> LN/ReLU/split -> HA ----
    mgemm_kernel<0, false><<<dim3(2, GY, 1), blk, 0, stream>>>(
        xhi, xlo, fc0Th, fc0Tl, fc0_b, FINf, nullptr, nullptr, M, 512, 256, 0, 0, 0, 0);
    ln_relu_split_kernel<<<dim3((M + 3) / 4), blk, 0, stream>>>(FINf, ln_w, ln_b, HAh, HAl, M);

    unsigned short* hinh = HAh; unsigned short* hinl = HAl;
    unsigned short* houth = HBh; unsigned short* houtl = HBl;

    for (int l = 0; l < 2; l++) {
        hipMemsetAsync(kvsf, 0, 1048576 + 4096 + 256, stream);
        // V
        mgemm_kernel<1, false><<<dim3(8, GY, 1), blk, 0, stream>>>(
            hinh, hinl, WvTh + (size_t)l * 262144, WvTl + (size_t)l * 262144,
            Wv_b + (size_t)l * 1024, nullptr, Vhi, Vlo, M, 256, 1024, 0, 0, 0, 0);
        // K
        mgemm_kernel<1, false><<<dim3(8, GY, 1), blk, 0, stream>>>(
            hinh, hinl, WkTh + (size_t)l * 262144, WkTl + (size_t)l * 262144,
            Wk_b + (size_t)l * 1024, nullptr, Khi, Klo, M, 256, 1024, 0, 0, 0, 0);
        stats_kernel<<<dim3(128), blk, 0, stream>>>(Khi, Klo, M, ssq + 0, ks);
        kvs_kernel<<<dim3(64, 8), blk, 0, stream>>>(Khi, Klo, Vhi, Vlo, kvsf, M);
        ktsplit_kernel<<<dim3(1024), blk, 0, stream>>>(kvsf, kvsTh, kvsTl);
        // Q (reuses K buffers)
        mgemm_kernel<1, false><<<dim3(8, GY, 1), blk, 0, stream>>>(
            hinh, hinl, WqTh + (size_t)l * 262144, WqTl + (size_t)l * 262144,
            Wq_b + (size_t)l * 1024, nullptr, Qhi, Qlo, M, 256, 1024, 0, 0, 0, 0);
        stats_kernel<<<dim3(128), blk, 0, stream>>>(Qhi, Qlo, M, ssq + 1, nullptr);
        den_kernel<<<dim3((M + 3) / 4), blk, 0, stream>>>(Qhi, Qlo, ks, den, M);
        qscale_kernel<<<dim3(50000), blk, 0, stream>>>(Qhi, Qlo, den, ssq, M);
        // fin = Q' @ stacked kvs  -> FINf
        mgemm_kernel<0, false><<<dim3(2, GY, 1), blk, 0, stream>>>(
            Qhi, Qlo, kvsTh, kvsTl, nullptr, FINf, nullptr, nullptr, M, 1024, 256, 0, 0, 0, 0);
        attn_ep_kernel<<<dim3((M + 3) / 4), blk, 0, stream>>>(
            FINf, Vhi, Vlo, den, ssq, hinh, hinl,
            ln_w + (size_t)(l + 1) * 256, ln_b + (size_t)(l + 1) * 256, houth, houtl, M);
        unsigned short* t;
        t = hinh; hinh = houth; houth = t;
        t = hinl; hinl = houtl; houtl = t;
    }
    // x1 = hin (HA pair); HB free

    // ---- SIGN branch ----
    split_kernel<<<dim3(100000), blk, 0, stream>>>(xs, (long)4 * M * 512 / 4, Xsh, Xsl);
    mgemm_kernel<1, true><<<dim3(1, GY, 4), blk, 0, stream>>>(
        Xsh, Xsl, mwTh, mwTl, mlp_b, nullptr, feath, featl,
        M, 512, 512, (long)M * 512, 65536, 128, 128);
    mgemm_kernel<0, false><<<dim3(2, GY, 1), blk, 0, stream>>>(
        feath, featl, mlTh, mlTl, mlp_lin_b, logitsf, nullptr, nullptr,
        M, 512, 256, 0, 0, 0, 0);
    lsm_combine_kernel<<<dim3((M + 3) / 4), blk, 0, stream>>>(logitsf, hinh, hinl, combf, M);
    sgemm_kernel<64, 64, 16, 4, 4, false><<<dim3(1, (M + 63) / 64), blk, 0, stream>>>(
        combf, fc_w, fc_b, out, M, 256, 256, 64, 64, 0, 0, 0, 0);
}